// Round 2
// baseline (962.412 us; speedup 1.0000x reference)
//
#include <hip/hip_runtime.h>

#define D   64
#define H   8
#define DH  8
#define ED  16
#define QK_SCALE 0.35355339059327373f   // 1/sqrt(8)

__device__ __forceinline__ void fma4(float4& a, float s, const float4& w) {
    a.x += s * w.x; a.y += s * w.y; a.z += s * w.z; a.w += s * w.w;
}

// ---------------------------------------------------------------------------
// K1: node projections q,k,v,x_r  ([N,64] each).  thread = (node, 4 cols),
//     64 nodes per block (4 iterations of 16) to amortize the 64KB W staging.
// ---------------------------------------------------------------------------
__global__ __launch_bounds__(256) void node_proj(
    const float* __restrict__ x,
    const float* __restrict__ Wq, const float* __restrict__ bq,
    const float* __restrict__ Wk, const float* __restrict__ bk,
    const float* __restrict__ Wv, const float* __restrict__ bv,
    const float* __restrict__ Ws, const float* __restrict__ bs,
    float* __restrict__ q, float* __restrict__ k,
    float* __restrict__ v, float* __restrict__ xr, int N)
{
    __shared__ float sW[4][D * D];          // 64 KB
    {
        const float* wsrc[4] = {Wq, Wk, Wv, Ws};
        for (int m = 0; m < 4; ++m)
            for (int t = threadIdx.x; t < D * D; t += 256)
                sW[m][t] = wsrc[m][t];
    }
    __syncthreads();

    int cg = (threadIdx.x & 15) * 4;
    float4 vbq = *(const float4*)(bq + cg);
    float4 vbk = *(const float4*)(bk + cg);
    float4 vbv = *(const float4*)(bv + cg);
    float4 vbs = *(const float4*)(bs + cg);

    #pragma unroll 1
    for (int it = 0; it < 4; ++it) {
        int node = blockIdx.x * 64 + it * 16 + (threadIdx.x >> 4);
        if (node >= N) return;

        float4 aq = {0,0,0,0}, ak = {0,0,0,0}, av = {0,0,0,0}, as_ = {0,0,0,0};
        const float* xrow = x + (size_t)node * D;

        #pragma unroll
        for (int i = 0; i < D; i += 4) {
            float4 xv = *(const float4*)(xrow + i);
            #pragma unroll
            for (int s = 0; s < 4; ++s) {
                float xs = (&xv.x)[s];
                fma4(aq, xs, *(const float4*)(&sW[0][(i + s) * D + cg]));
                fma4(ak, xs, *(const float4*)(&sW[1][(i + s) * D + cg]));
                fma4(av, xs, *(const float4*)(&sW[2][(i + s) * D + cg]));
                fma4(as_, xs, *(const float4*)(&sW[3][(i + s) * D + cg]));
            }
        }
        aq.x += vbq.x; aq.y += vbq.y; aq.z += vbq.z; aq.w += vbq.w;
        ak.x += vbk.x; ak.y += vbk.y; ak.z += vbk.z; ak.w += vbk.w;
        av.x += vbv.x; av.y += vbv.y; av.z += vbv.z; av.w += vbv.w;
        as_.x += vbs.x; as_.y += vbs.y; as_.z += vbs.z; as_.w += vbs.w;

        size_t o = (size_t)node * D + cg;
        *(float4*)(q  + o) = aq;
        *(float4*)(k  + o) = ak;
        *(float4*)(v  + o) = av;
        *(float4*)(xr + o) = as_;
    }
}

// ---------------------------------------------------------------------------
// K2: edge pass. wave = 4 edges, 16 lanes/edge, lane = 4 cols (float4).
//     All gathers/atomics for 4 edges issue in the same instructions -> 4x MLP.
// ---------------------------------------------------------------------------
__global__ __launch_bounds__(256, 8) void edge_pass(
    const int*   __restrict__ ei,
    const float* __restrict__ ea,
    const float* __restrict__ We, const float* __restrict__ be,
    const float* __restrict__ q, const float* __restrict__ k,
    const float* __restrict__ v,
    float* __restrict__ denom, float* __restrict__ out_acc, int E)
{
    __shared__ float sWe[ED * D];   // 4 KB
    __shared__ float sbe[D];
    for (int t = threadIdx.x; t < ED * D; t += 256) sWe[t] = We[t];
    if (threadIdx.x < D) sbe[threadIdx.x] = be[threadIdx.x];
    __syncthreads();

    int lane = threadIdx.x & 63;
    int l    = lane & 15;           // lane within edge group
    int g    = lane >> 4;           // edge slot 0..3
    int c4   = l * 4;               // first column this lane owns
    float4 vbe = *(const float4*)(sbe + c4);

    long w0 = (long)blockIdx.x * 4 + (threadIdx.x >> 6);
    long stride = (long)gridDim.x * 4 * 4;   // waves * 4 edges

    for (long e0 = w0 * 4; e0 < E; e0 += stride) {
        long e = e0 + g;
        bool valid = e < E;
        long ec = valid ? e : (long)(E - 1);

        int src = ei[ec];
        int dst = ei[E + ec];

        // e-projection for this lane's 4 columns
        const float4* eap = (const float4*)(ea + ec * ED);
        float4 a0 = eap[0], a1 = eap[1], a2 = eap[2], a3 = eap[3];
        float ev[16];
        *(float4*)(ev + 0)  = a0; *(float4*)(ev + 4)  = a1;
        *(float4*)(ev + 8)  = a2; *(float4*)(ev + 12) = a3;

        float4 acc = vbe;
        #pragma unroll
        for (int i = 0; i < ED; ++i)
            fma4(acc, ev[i], *(const float4*)(sWe + i * D + c4));

        const size_t so = (size_t)src * D + c4;
        const size_t doff = (size_t)dst * D + c4;
        float4 kv = *(const float4*)(k + so);
        float4 vv = *(const float4*)(v + so);
        float4 qv = *(const float4*)(q + doff);

        float4 ke = {kv.x + acc.x, kv.y + acc.y, kv.z + acc.z, kv.w + acc.w};
        float t = qv.x * ke.x + qv.y * ke.y + qv.z * ke.z + qv.w * ke.w;
        t += __shfl_xor(t, 1);      // pair lanes (2h,2h+1) share head h
        float p = __expf(t * QK_SCALE);

        if (valid) {
            if ((l & 1) == 0)
                unsafeAtomicAdd(&denom[(size_t)dst * H + (l >> 1)], p);
            float* outp = out_acc + doff;
            unsafeAtomicAdd(outp + 0, p * (vv.x + acc.x));
            unsafeAtomicAdd(outp + 1, p * (vv.y + acc.y));
            unsafeAtomicAdd(outp + 2, p * (vv.z + acc.z));
            unsafeAtomicAdd(outp + 3, p * (vv.w + acc.w));
        }
    }
}

// ---------------------------------------------------------------------------
// K3: node epilogue. wave per node; lane = column.
// ---------------------------------------------------------------------------
__global__ __launch_bounds__(256) void node_epi(
    const float* __restrict__ out_acc, const float* __restrict__ denom,
    const float* __restrict__ xr, const float* __restrict__ Wbeta,
    float* __restrict__ out2, float* __restrict__ S1, float* __restrict__ S2,
    int N)
{
    __shared__ float ls1[4][D];
    __shared__ float ls2[4][D];
    int lane = threadIdx.x & 63;
    int w    = threadIdx.x >> 6;
    float wb0 = Wbeta[lane], wb1 = Wbeta[D + lane], wb2 = Wbeta[2 * D + lane];
    float s1 = 0.f, s2 = 0.f;

    long gw = (long)blockIdx.x * 4 + w;
    long nw = (long)gridDim.x * 4;
    for (long nid = gw; nid < N; nid += nw) {
        float acc = out_acc[nid * D + lane];
        float dnm = denom[nid * H + (lane >> 3)];
        float o   = acc / (dnm + 1e-16f);
        float xrv = xr[nid * D + lane];
        float t = o * wb0 + xrv * wb1 + (o - xrv) * wb2;
        #pragma unroll
        for (int s = 1; s < 64; s <<= 1) t += __shfl_xor(t, s);
        float g  = 1.f / (1.f + __expf(-t));
        float o2 = g * xrv + (1.f - g) * o;
        out2[nid * D + lane] = o2;
        s1 += o2; s2 += o2 * o2;
    }
    ls1[w][lane] = s1; ls2[w][lane] = s2;
    __syncthreads();
    if (threadIdx.x < D) {
        float a = ls1[0][lane] + ls1[1][lane] + ls1[2][lane] + ls1[3][lane];
        float b = ls2[0][lane] + ls2[1][lane] + ls2[2][lane] + ls2[3][lane];
        unsafeAtomicAdd(&S1[lane], a);
        unsafeAtomicAdd(&S2[lane], b);
    }
}

// ---------------------------------------------------------------------------
// K4: batchnorm finalize + apply + LeakyReLU, float4 in place on d_out.
// ---------------------------------------------------------------------------
__global__ __launch_bounds__(256) void bn_apply(
    float4* __restrict__ out, const float* __restrict__ S1,
    const float* __restrict__ S2, const float* __restrict__ gamma,
    const float* __restrict__ beta, int total4, float invN)
{
    int gid = blockIdx.x * 256 + threadIdx.x;
    if (gid >= total4) return;
    int col = (gid & 15) * 4;
    float4 m4 = *(const float4*)(S1 + col);
    float4 v4 = *(const float4*)(S2 + col);
    float4 g4 = *(const float4*)(gamma + col);
    float4 b4 = *(const float4*)(beta + col);
    float4 y  = out[gid];
    #pragma unroll
    for (int j = 0; j < 4; ++j) {
        float mean = (&m4.x)[j] * invN;
        float var  = (&v4.x)[j] * invN - mean * mean;
        float sc   = (&g4.x)[j] * rsqrtf(var + 1e-5f);
        float sh   = (&b4.x)[j] - mean * sc;
        float t    = (&y.x)[j] * sc + sh;
        (&y.x)[j]  = (t >= 0.f) ? t : 0.01f * t;
    }
    out[gid] = y;
}

// ---------------------------------------------------------------------------
extern "C" void kernel_launch(void* const* d_in, const int* in_sizes, int n_in,
                              void* d_out, int out_size, void* d_ws, size_t ws_size,
                              hipStream_t stream)
{
    const float* x     = (const float*)d_in[0];
    const int*   ei    = (const int*)  d_in[1];
    const float* ea    = (const float*)d_in[2];
    const float* Wq    = (const float*)d_in[3];
    const float* bq    = (const float*)d_in[4];
    const float* Wk    = (const float*)d_in[5];
    const float* bk    = (const float*)d_in[6];
    const float* Wv    = (const float*)d_in[7];
    const float* bv    = (const float*)d_in[8];
    const float* We    = (const float*)d_in[9];
    const float* be    = (const float*)d_in[10];
    const float* Wskip = (const float*)d_in[11];
    const float* bskip = (const float*)d_in[12];
    const float* Wbeta = (const float*)d_in[13];
    const float* gamma = (const float*)d_in[14];
    const float* betab = (const float*)d_in[15];

    int N = in_sizes[0] / D;
    int E = in_sizes[1] / 2;

    float* ws      = (float*)d_ws;
    float* denom   = ws;                          // N*8
    float* out_acc = denom + (size_t)N * H;       // N*64
    float* S1      = out_acc + (size_t)N * D;     // 64
    float* S2      = S1 + D;                      // 64
    float* q       = S2 + D;                      // N*64
    float* k       = q + (size_t)N * D;
    float* v       = k + (size_t)N * D;
    float* xr      = v + (size_t)N * D;

    // zero the accumulators (denom, out_acc, S1, S2 are contiguous)
    hipMemsetAsync(denom, 0, ((size_t)N * (H + D) + 2 * D) * sizeof(float), stream);

    node_proj<<<(N + 63) / 64, 256, 0, stream>>>(
        x, Wq, bq, Wk, bk, Wv, bv, Wskip, bskip, q, k, v, xr, N);

    edge_pass<<<2048, 256, 0, stream>>>(
        ei, ea, We, be, q, k, v, denom, out_acc, E);

    node_epi<<<2048, 256, 0, stream>>>(
        out_acc, denom, xr, Wbeta, (float*)d_out, S1, S2, N);

    bn_apply<<<(N * 16 + 255) / 256, 256, 0, stream>>>(
        (float4*)d_out, S1, S2, gamma, betab, N * 16, 1.0f / (float)N);
}

// Round 3
// 353.077 us; speedup vs baseline: 2.7258x; 2.7258x over previous
//
#include <hip/hip_runtime.h>

#define D   64
#define H   8
#define DH  8
#define ED  16
#define QK_SCALE 0.35355339059327373f   // 1/sqrt(8)

__device__ __forceinline__ void fma4(float4& a, float s, const float4& w) {
    a.x += s * w.x; a.y += s * w.y; a.z += s * w.z; a.w += s * w.w;
}

__device__ __forceinline__ float bcast(float v, int srclane) {
    return __uint_as_float(__builtin_amdgcn_readlane(__float_as_uint(v), srclane));
}

// ---------------------------------------------------------------------------
// K1: node projections q,k,v,x_r  ([N,64] each).  thread = (node, 4 cols),
//     64 nodes per block to amortize the 64KB W staging.
// ---------------------------------------------------------------------------
__global__ __launch_bounds__(256) void node_proj(
    const float* __restrict__ x,
    const float* __restrict__ Wq, const float* __restrict__ bq,
    const float* __restrict__ Wk, const float* __restrict__ bk,
    const float* __restrict__ Wv, const float* __restrict__ bv,
    const float* __restrict__ Ws, const float* __restrict__ bs,
    float* __restrict__ q, float* __restrict__ k,
    float* __restrict__ v, float* __restrict__ xr, int N)
{
    __shared__ float sW[4][D * D];          // 64 KB
    {
        const float* wsrc[4] = {Wq, Wk, Wv, Ws};
        for (int m = 0; m < 4; ++m)
            for (int t = threadIdx.x; t < D * D; t += 256)
                sW[m][t] = wsrc[m][t];
    }
    __syncthreads();

    int cg = (threadIdx.x & 15) * 4;
    float4 vbq = *(const float4*)(bq + cg);
    float4 vbk = *(const float4*)(bk + cg);
    float4 vbv = *(const float4*)(bv + cg);
    float4 vbs = *(const float4*)(bs + cg);

    #pragma unroll 1
    for (int it = 0; it < 4; ++it) {
        int node = blockIdx.x * 64 + it * 16 + (threadIdx.x >> 4);
        if (node >= N) return;

        float4 aq = {0,0,0,0}, ak = {0,0,0,0}, av = {0,0,0,0}, as_ = {0,0,0,0};
        const float* xrow = x + (size_t)node * D;

        #pragma unroll
        for (int i = 0; i < D; i += 4) {
            float4 xv = *(const float4*)(xrow + i);
            #pragma unroll
            for (int s = 0; s < 4; ++s) {
                float xs = (&xv.x)[s];
                fma4(aq, xs, *(const float4*)(&sW[0][(i + s) * D + cg]));
                fma4(ak, xs, *(const float4*)(&sW[1][(i + s) * D + cg]));
                fma4(av, xs, *(const float4*)(&sW[2][(i + s) * D + cg]));
                fma4(as_, xs, *(const float4*)(&sW[3][(i + s) * D + cg]));
            }
        }
        aq.x += vbq.x; aq.y += vbq.y; aq.z += vbq.z; aq.w += vbq.w;
        ak.x += vbk.x; ak.y += vbk.y; ak.z += vbk.z; ak.w += vbk.w;
        av.x += vbv.x; av.y += vbv.y; av.z += vbv.z; av.w += vbv.w;
        as_.x += vbs.x; as_.y += vbs.y; as_.z += vbs.z; as_.w += vbs.w;

        size_t o = (size_t)node * D + cg;
        *(float4*)(q  + o) = aq;
        *(float4*)(k  + o) = ak;
        *(float4*)(v  + o) = av;
        *(float4*)(xr + o) = as_;
    }
}

// ---------------------------------------------------------------------------
// K2: edge pass. wave = 4 consecutive edges per iteration; lane = column.
//     R1 memory shape (contiguous 64-lane row loads & atomics) + 4-way MLP.
//     We column held in 16 registers; ea broadcast via readlane. Zero LDS.
// ---------------------------------------------------------------------------
__global__ __launch_bounds__(256, 8) void edge_pass(
    const int*   __restrict__ ei,
    const float* __restrict__ ea,
    const float* __restrict__ We, const float* __restrict__ be,
    const float* __restrict__ q, const float* __restrict__ k,
    const float* __restrict__ v,
    float* __restrict__ denom, float* __restrict__ out_acc, int E)
{
    int lane = threadIdx.x & 63;

    // We column for this lane, in registers
    float rWe[ED];
    #pragma unroll
    for (int i = 0; i < ED; ++i) rWe[i] = We[i * D + lane];
    float bev = be[lane];

    long wid = (long)blockIdx.x * 4 + (threadIdx.x >> 6);
    long nw  = (long)gridDim.x * 4;

    for (long e0 = wid * 4; e0 < E; e0 += nw * 4) {
        // ---- issue phase: all loads for 4 edges ----
        int src[4], dst[4];
        #pragma unroll
        for (int j = 0; j < 4; ++j) {
            long e = e0 + j; if (e >= E) e = E - 1;
            src[j] = ei[e];
            dst[j] = ei[E + e];
        }
        // cooperative ea load: 64 consecutive floats = ea[e0..e0+3][0..15]
        long eaidx = e0 * ED + lane;
        if (eaidx >= (long)E * ED) eaidx = (long)E * ED - 1;
        float eav = ea[eaidx];

        float kv[4], vv[4], qv[4];
        #pragma unroll
        for (int j = 0; j < 4; ++j) {
            size_t so = (size_t)src[j] * D + lane;
            size_t dofs = (size_t)dst[j] * D + lane;
            kv[j] = k[so];
            vv[j] = v[so];
            qv[j] = q[dofs];
        }

        // ---- compute phase ----
        float p[4], ov[4];
        #pragma unroll
        for (int j = 0; j < 4; ++j) {
            float ecol = bev;
            #pragma unroll
            for (int i = 0; i < ED; ++i)
                ecol += bcast(eav, j * 16 + i) * rWe[i];
            float ke = kv[j] + ecol;
            float t  = qv[j] * ke;
            t += __shfl_xor(t, 1);
            t += __shfl_xor(t, 2);
            t += __shfl_xor(t, 4);
            p[j]  = __expf(t * QK_SCALE);
            ov[j] = p[j] * (vv[j] + ecol);
        }

        // ---- atomic phase: contiguous full-row adds, one edge at a time ----
        #pragma unroll
        for (int j = 0; j < 4; ++j) {
            if (e0 + j < E) {
                if ((lane & 7) == 0)
                    unsafeAtomicAdd(&denom[(size_t)dst[j] * H + (lane >> 3)], p[j]);
                unsafeAtomicAdd(&out_acc[(size_t)dst[j] * D + lane], ov[j]);
            }
        }
    }
}

// ---------------------------------------------------------------------------
// K3: node epilogue. wave per node; lane = column.
// ---------------------------------------------------------------------------
__global__ __launch_bounds__(256) void node_epi(
    const float* __restrict__ out_acc, const float* __restrict__ denom,
    const float* __restrict__ xr, const float* __restrict__ Wbeta,
    float* __restrict__ out2, float* __restrict__ S1, float* __restrict__ S2,
    int N)
{
    __shared__ float ls1[4][D];
    __shared__ float ls2[4][D];
    int lane = threadIdx.x & 63;
    int w    = threadIdx.x >> 6;
    float wb0 = Wbeta[lane], wb1 = Wbeta[D + lane], wb2 = Wbeta[2 * D + lane];
    float s1 = 0.f, s2 = 0.f;

    long gw = (long)blockIdx.x * 4 + w;
    long nw = (long)gridDim.x * 4;
    for (long nid = gw; nid < N; nid += nw) {
        float acc = out_acc[nid * D + lane];
        float dnm = denom[nid * H + (lane >> 3)];
        float o   = acc / (dnm + 1e-16f);
        float xrv = xr[nid * D + lane];
        float t = o * wb0 + xrv * wb1 + (o - xrv) * wb2;
        #pragma unroll
        for (int s = 1; s < 64; s <<= 1) t += __shfl_xor(t, s);
        float g  = 1.f / (1.f + __expf(-t));
        float o2 = g * xrv + (1.f - g) * o;
        out2[nid * D + lane] = o2;
        s1 += o2; s2 += o2 * o2;
    }
    ls1[w][lane] = s1; ls2[w][lane] = s2;
    __syncthreads();
    if (threadIdx.x < D) {
        float a = ls1[0][lane] + ls1[1][lane] + ls1[2][lane] + ls1[3][lane];
        float b = ls2[0][lane] + ls2[1][lane] + ls2[2][lane] + ls2[3][lane];
        unsafeAtomicAdd(&S1[lane], a);
        unsafeAtomicAdd(&S2[lane], b);
    }
}

// ---------------------------------------------------------------------------
// K4: batchnorm finalize + apply + LeakyReLU, float4 in place on d_out.
// ---------------------------------------------------------------------------
__global__ __launch_bounds__(256) void bn_apply(
    float4* __restrict__ out, const float* __restrict__ S1,
    const float* __restrict__ S2, const float* __restrict__ gamma,
    const float* __restrict__ beta, int total4, float invN)
{
    int gid = blockIdx.x * 256 + threadIdx.x;
    if (gid >= total4) return;
    int col = (gid & 15) * 4;
    float4 m4 = *(const float4*)(S1 + col);
    float4 v4 = *(const float4*)(S2 + col);
    float4 g4 = *(const float4*)(gamma + col);
    float4 b4 = *(const float4*)(beta + col);
    float4 y  = out[gid];
    #pragma unroll
    for (int j = 0; j < 4; ++j) {
        float mean = (&m4.x)[j] * invN;
        float var  = (&v4.x)[j] * invN - mean * mean;
        float sc   = (&g4.x)[j] * rsqrtf(var + 1e-5f);
        float sh   = (&b4.x)[j] - mean * sc;
        float t    = (&y.x)[j] * sc + sh;
        (&y.x)[j]  = (t >= 0.f) ? t : 0.01f * t;
    }
    out[gid] = y;
}

// ---------------------------------------------------------------------------
extern "C" void kernel_launch(void* const* d_in, const int* in_sizes, int n_in,
                              void* d_out, int out_size, void* d_ws, size_t ws_size,
                              hipStream_t stream)
{
    const float* x     = (const float*)d_in[0];
    const int*   ei    = (const int*)  d_in[1];
    const float* ea    = (const float*)d_in[2];
    const float* Wq    = (const float*)d_in[3];
    const float* bq    = (const float*)d_in[4];
    const float* Wk    = (const float*)d_in[5];
    const float* bk    = (const float*)d_in[6];
    const float* Wv    = (const float*)d_in[7];
    const float* bv    = (const float*)d_in[8];
    const float* We    = (const float*)d_in[9];
    const float* be    = (const float*)d_in[10];
    const float* Wskip = (const float*)d_in[11];
    const float* bskip = (const float*)d_in[12];
    const float* Wbeta = (const float*)d_in[13];
    const float* gamma = (const float*)d_in[14];
    const float* betab = (const float*)d_in[15];

    int N = in_sizes[0] / D;
    int E = in_sizes[1] / 2;

    float* ws      = (float*)d_ws;
    float* denom   = ws;                          // N*8
    float* out_acc = denom + (size_t)N * H;       // N*64
    float* S1      = out_acc + (size_t)N * D;     // 64
    float* S2      = S1 + D;                      // 64
    float* q       = S2 + D;                      // N*64
    float* k       = q + (size_t)N * D;
    float* v       = k + (size_t)N * D;
    float* xr      = v + (size_t)N * D;

    // zero the accumulators (denom, out_acc, S1, S2 are contiguous)
    hipMemsetAsync(denom, 0, ((size_t)N * (H + D) + 2 * D) * sizeof(float), stream);

    node_proj<<<(N + 63) / 64, 256, 0, stream>>>(
        x, Wq, bq, Wk, bk, Wv, bv, Wskip, bskip, q, k, v, xr, N);

    edge_pass<<<2048, 256, 0, stream>>>(
        ei, ea, We, be, q, k, v, denom, out_acc, E);

    node_epi<<<2048, 256, 0, stream>>>(
        out_acc, denom, xr, Wbeta, (float*)d_out, S1, S2, N);

    bn_apply<<<(N * 16 + 255) / 256, 256, 0, stream>>>(
        (float4*)d_out, S1, S2, gamma, betab, N * 16, 1.0f / (float)N);
}

// Round 4
// 303.999 us; speedup vs baseline: 3.1658x; 1.1614x over previous
//
#include <hip/hip_runtime.h>

#define D   64
#define H   8
#define DH  8
#define ED  16
#define QK_SCALE 0.35355339059327373f   // 1/sqrt(8)

__device__ __forceinline__ void fma4(float4& a, float s, const float4& w) {
    a.x += s * w.x; a.y += s * w.y; a.z += s * w.z; a.w += s * w.w;
}
__device__ __forceinline__ float bcastf(float v, int srclane) {
    return __uint_as_float(__builtin_amdgcn_readlane(__float_as_uint(v), srclane));
}

// ---------------------------------------------------------------------------
// K1: node projections q,k,v,x_r  ([N,64] each). 64 nodes/block.
// ---------------------------------------------------------------------------
__global__ __launch_bounds__(256) void node_proj(
    const float* __restrict__ x,
    const float* __restrict__ Wq, const float* __restrict__ bq,
    const float* __restrict__ Wk, const float* __restrict__ bk,
    const float* __restrict__ Wv, const float* __restrict__ bv,
    const float* __restrict__ Ws, const float* __restrict__ bs,
    float* __restrict__ q, float* __restrict__ k,
    float* __restrict__ v, float* __restrict__ xr, int N)
{
    __shared__ float sW[4][D * D];          // 64 KB
    {
        const float* wsrc[4] = {Wq, Wk, Wv, Ws};
        for (int m = 0; m < 4; ++m)
            for (int t = threadIdx.x; t < D * D; t += 256)
                sW[m][t] = wsrc[m][t];
    }
    __syncthreads();

    int cg = (threadIdx.x & 15) * 4;
    float4 vbq = *(const float4*)(bq + cg);
    float4 vbk = *(const float4*)(bk + cg);
    float4 vbv = *(const float4*)(bv + cg);
    float4 vbs = *(const float4*)(bs + cg);

    #pragma unroll 1
    for (int it = 0; it < 4; ++it) {
        int node = blockIdx.x * 64 + it * 16 + (threadIdx.x >> 4);
        if (node >= N) return;

        float4 aq = {0,0,0,0}, ak = {0,0,0,0}, av = {0,0,0,0}, as_ = {0,0,0,0};
        const float* xrow = x + (size_t)node * D;

        #pragma unroll
        for (int i = 0; i < D; i += 4) {
            float4 xv = *(const float4*)(xrow + i);
            #pragma unroll
            for (int s = 0; s < 4; ++s) {
                float xs = (&xv.x)[s];
                fma4(aq, xs, *(const float4*)(&sW[0][(i + s) * D + cg]));
                fma4(ak, xs, *(const float4*)(&sW[1][(i + s) * D + cg]));
                fma4(av, xs, *(const float4*)(&sW[2][(i + s) * D + cg]));
                fma4(as_, xs, *(const float4*)(&sW[3][(i + s) * D + cg]));
            }
        }
        aq.x += vbq.x; aq.y += vbq.y; aq.z += vbq.z; aq.w += vbq.w;
        ak.x += vbk.x; ak.y += vbk.y; ak.z += vbk.z; ak.w += vbk.w;
        av.x += vbv.x; av.y += vbv.y; av.z += vbv.z; av.w += vbv.w;
        as_.x += vbs.x; as_.y += vbs.y; as_.z += vbs.z; as_.w += vbs.w;

        size_t o = (size_t)node * D + cg;
        *(float4*)(q  + o) = aq;
        *(float4*)(k  + o) = ak;
        *(float4*)(v  + o) = av;
        *(float4*)(xr + o) = as_;
    }
}

// ---------------------------------------------------------------------------
// CSR build: histogram -> block scan (3 stages) -> scatter
// ---------------------------------------------------------------------------
__global__ __launch_bounds__(256) void csr_hist(
    const int* __restrict__ ei, int* __restrict__ cnt, int E)
{
    int gid = blockIdx.x * 256 + threadIdx.x;
    if (gid < E) atomicAdd(&cnt[ei[E + gid]], 1);
}

__global__ __launch_bounds__(256) void scan_a(
    const int* __restrict__ cnt, int* __restrict__ bsum, int N)
{
    __shared__ int red[256];
    int t = threadIdx.x;
    int i = blockIdx.x * 256 + t;
    red[t] = (i < N) ? cnt[i] : 0;
    __syncthreads();
    for (int s = 128; s > 0; s >>= 1) {
        if (t < s) red[t] += red[t + s];
        __syncthreads();
    }
    if (t == 0) bsum[blockIdx.x] = red[0];
}

__global__ __launch_bounds__(256) void scan_b(int* __restrict__ bsum, int nb)
{
    __shared__ int sh[256];
    int t = threadIdx.x;
    int v = (t < nb) ? bsum[t] : 0;
    sh[t] = v;
    __syncthreads();
    for (int s = 1; s < 256; s <<= 1) {
        int a = (t >= s) ? sh[t - s] : 0;
        __syncthreads();
        sh[t] += a;
        __syncthreads();
    }
    if (t < nb) bsum[t] = sh[t] - v;   // exclusive
}

__global__ __launch_bounds__(256) void scan_c(
    const int* __restrict__ cnt, const int* __restrict__ bsum,
    int* __restrict__ row_start, int* __restrict__ cursor, int N, int E)
{
    __shared__ int sh[256];
    int t = threadIdx.x;
    int i = blockIdx.x * 256 + t;
    int v = (i < N) ? cnt[i] : 0;
    sh[t] = v;
    __syncthreads();
    for (int s = 1; s < 256; s <<= 1) {
        int a = (t >= s) ? sh[t - s] : 0;
        __syncthreads();
        sh[t] += a;
        __syncthreads();
    }
    int excl = sh[t] - v + bsum[blockIdx.x];
    if (i < N) { row_start[i] = excl; cursor[i] = excl; }
    if (i == N - 1) row_start[N] = E;
}

__global__ __launch_bounds__(256) void csr_scatter(
    const int* __restrict__ ei, int* __restrict__ cursor,
    int* __restrict__ csr, int E)
{
    int gid = blockIdx.x * 256 + threadIdx.x;
    if (gid < E) {
        int d = ei[E + gid];
        int pos = atomicAdd(&cursor[d], 1);
        csr[pos] = gid;
    }
}

// ---------------------------------------------------------------------------
// K2: pull-mode gather. wave = dst node, lane = column. Register accumulation,
//     zero hot-path atomics. Fused node epilogue (alpha-norm, beta gate).
// ---------------------------------------------------------------------------
__global__ __launch_bounds__(256, 8) void node_gather(
    const int*   __restrict__ ei,        // [2,E], row 0 = src
    const float* __restrict__ ea,
    const int*   __restrict__ row_start, // [N+1]
    const int*   __restrict__ csr,       // [E]
    const float* __restrict__ We, const float* __restrict__ be,
    const float* __restrict__ q, const float* __restrict__ k,
    const float* __restrict__ v, const float* __restrict__ xr,
    const float* __restrict__ Wbeta,
    float* __restrict__ out, int N)
{
    int lane = threadIdx.x & 63;
    int nid  = blockIdx.x * 4 + (threadIdx.x >> 6);
    if (nid >= N) return;

    float rWe[ED];
    #pragma unroll
    for (int i = 0; i < ED; ++i) rWe[i] = We[i * D + lane];
    float bev = be[lane];

    int rs  = row_start[nid];
    int re  = row_start[nid + 1];
    int deg = re - rs;

    float qv  = q[(size_t)nid * D + lane];
    float acc = 0.f, den = 0.f;

    // lane-parallel edge-id / src prefetch (covers deg<=64; rare tail below)
    int eidv = 0, srcv = 0;
    if (lane < deg) { eidv = csr[rs + lane]; srcv = ei[eidv]; }

    int nb = (deg < 64) ? deg : 64;
    for (int j0 = 0; j0 < nb; j0 += 4) {
        int m = nb - j0; if (m > 4) m = 4;
        float kvv[4], vvv[4], eav[4];
        #pragma unroll
        for (int j = 0; j < 4; ++j) {
            int jj  = (j < m) ? (j0 + j) : j0;
            int s   = __builtin_amdgcn_readlane(srcv, jj);
            int eid = __builtin_amdgcn_readlane(eidv, jj);
            kvv[j] = k[(size_t)s * D + lane];
            vvv[j] = v[(size_t)s * D + lane];
            eav[j] = ea[(size_t)eid * ED + (lane & 15)];
        }
        #pragma unroll
        for (int j = 0; j < 4; ++j) {
            if (j < m) {
                float ecol = bev;
                #pragma unroll
                for (int i = 0; i < ED; ++i)
                    ecol += bcastf(eav[j], i) * rWe[i];
                float ke = kvv[j] + ecol;
                float t  = qv * ke;
                t += __shfl_xor(t, 1);
                t += __shfl_xor(t, 2);
                t += __shfl_xor(t, 4);
                float p = __expf(t * QK_SCALE);
                acc += p * (vvv[j] + ecol);
                den += p;
            }
        }
    }
    // rare fallback: degree > 64
    for (int j = 64; j < deg; ++j) {
        int eid = csr[rs + j];
        int s   = ei[eid];
        float kvv = k[(size_t)s * D + lane];
        float vvv = v[(size_t)s * D + lane];
        float eav = ea[(size_t)eid * ED + (lane & 15)];
        float ecol = bev;
        #pragma unroll
        for (int i = 0; i < ED; ++i)
            ecol += bcastf(eav, i) * rWe[i];
        float ke = kvv + ecol;
        float t  = qv * ke;
        t += __shfl_xor(t, 1);
        t += __shfl_xor(t, 2);
        t += __shfl_xor(t, 4);
        float p = __expf(t * QK_SCALE);
        acc += p * (vvv + ecol);
        den += p;
    }

    // fused epilogue: alpha-normalize + beta gate + write
    float o   = acc / (den + 1e-16f);
    float xrv = xr[(size_t)nid * D + lane];
    float wb0 = Wbeta[lane], wb1 = Wbeta[D + lane], wb2 = Wbeta[2 * D + lane];
    float t = o * wb0 + xrv * wb1 + (o - xrv) * wb2;
    #pragma unroll
    for (int s = 1; s < 64; s <<= 1) t += __shfl_xor(t, s);
    float g = 1.f / (1.f + __expf(-t));
    out[(size_t)nid * D + lane] = g * xrv + (1.f - g) * o;
}

// ---------------------------------------------------------------------------
// K3: BN column sums from d_out (channel-padded atomics: stride 64 floats).
// ---------------------------------------------------------------------------
__global__ __launch_bounds__(256) void bn_stats(
    const float* __restrict__ out, float* __restrict__ S1p,
    float* __restrict__ S2p, int N, int rpb)
{
    __shared__ float l1[4][D];
    __shared__ float l2[4][D];
    int t = threadIdx.x, lane = t & 63, w = t >> 6;
    long r0 = (long)blockIdx.x * rpb;
    long rend = r0 + rpb; if (rend > N) rend = N;
    float s1 = 0.f, s2 = 0.f;
    for (long r = r0 + w; r < rend; r += 4) {
        float y = out[r * D + lane];
        s1 += y; s2 += y * y;
    }
    l1[w][lane] = s1; l2[w][lane] = s2;
    __syncthreads();
    if (t < D) {
        float a = l1[0][t] + l1[1][t] + l1[2][t] + l1[3][t];
        float b = l2[0][t] + l2[1][t] + l2[2][t] + l2[3][t];
        unsafeAtomicAdd(&S1p[t * 64], a);
        unsafeAtomicAdd(&S2p[t * 64], b);
    }
}

// ---------------------------------------------------------------------------
// K4: batchnorm finalize + apply + LeakyReLU, float4 in place on d_out.
// ---------------------------------------------------------------------------
__global__ __launch_bounds__(256) void bn_apply(
    float4* __restrict__ out, const float* __restrict__ S1p,
    const float* __restrict__ S2p, const float* __restrict__ gamma,
    const float* __restrict__ beta, int total4, float invN)
{
    int gid = blockIdx.x * 256 + threadIdx.x;
    if (gid >= total4) return;
    int col = (gid & 15) * 4;
    float4 g4 = *(const float4*)(gamma + col);
    float4 b4 = *(const float4*)(beta + col);
    float4 y  = out[gid];
    #pragma unroll
    for (int j = 0; j < 4; ++j) {
        float mean = S1p[(col + j) * 64] * invN;
        float var  = S2p[(col + j) * 64] * invN - mean * mean;
        float sc   = (&g4.x)[j] * rsqrtf(var + 1e-5f);
        float sh   = (&b4.x)[j] - mean * sc;
        float tv   = (&y.x)[j] * sc + sh;
        (&y.x)[j]  = (tv >= 0.f) ? tv : 0.01f * tv;
    }
    out[gid] = y;
}

// ---------------------------------------------------------------------------
extern "C" void kernel_launch(void* const* d_in, const int* in_sizes, int n_in,
                              void* d_out, int out_size, void* d_ws, size_t ws_size,
                              hipStream_t stream)
{
    const float* x     = (const float*)d_in[0];
    const int*   ei    = (const int*)  d_in[1];
    const float* ea    = (const float*)d_in[2];
    const float* Wq    = (const float*)d_in[3];
    const float* bq    = (const float*)d_in[4];
    const float* Wk    = (const float*)d_in[5];
    const float* bk    = (const float*)d_in[6];
    const float* Wv    = (const float*)d_in[7];
    const float* bv    = (const float*)d_in[8];
    const float* We    = (const float*)d_in[9];
    const float* be    = (const float*)d_in[10];
    const float* Wskip = (const float*)d_in[11];
    const float* bskip = (const float*)d_in[12];
    const float* Wbeta = (const float*)d_in[13];
    const float* gamma = (const float*)d_in[14];
    const float* betab = (const float*)d_in[15];

    int N = in_sizes[0] / D;
    int E = in_sizes[1] / 2;

    // ws layout (4B units, 16B-aligned regions)
    int*   cnt       = (int*)d_ws;                       // N
    float* S1p       = (float*)d_ws + 50000;             // 4096 (padded col sums)
    float* S2p       = S1p + 4096;                       // 4096
    int*   row_start = (int*)(S2p + 4096);               // N+1 (pad to 50004)
    int*   cursor    = row_start + 50004;                // N
    int*   csr       = cursor + 50000;                   // E
    float* q         = (float*)(csr + 800000 + ((4 - (800000 & 3)) & 3));
    float* k         = q + (size_t)N * D;
    float* v         = k + (size_t)N * D;
    float* xr        = v + (size_t)N * D;

    // zero cnt + S1p + S2p (contiguous from base)
    hipMemsetAsync(d_ws, 0, (size_t)(50000 + 8192) * sizeof(int), stream);

    node_proj<<<(N + 63) / 64, 256, 0, stream>>>(
        x, Wq, bq, Wk, bk, Wv, bv, Wskip, bskip, q, k, v, xr, N);

    int nb = (N + 255) / 256;   // 196 scan blocks
    csr_hist<<<(E + 255) / 256, 256, 0, stream>>>(ei, cnt, E);
    scan_a<<<nb, 256, 0, stream>>>(cnt, cursor, N);      // reuse cursor as bsum temp? no:
    // NOTE: bsum must persist; use tail of S2p padding? keep it simple: use csr head
    // (csr not yet written) -- but scatter follows scan. Use dedicated small buf:
    // place bsum in S2p+... safer: reuse cnt? cnt still needed by scan_c. Use csr[0..255].
    scan_b<<<1, 256, 0, stream>>>(cursor, nb);
    scan_c<<<nb, 256, 0, stream>>>(cnt, cursor, row_start, cnt /*cursor2*/, N, E);
    // cursor array was consumed as bsum; reuse cnt as the scatter cursor
    csr_scatter<<<(E + 255) / 256, 256, 0, stream>>>(ei, cnt, csr, E);

    node_gather<<<(N + 3) / 4, 256, 0, stream>>>(
        ei, ea, row_start, csr, We, be, q, k, v, xr, Wbeta, (float*)d_out, N);

    int rpb = (N + 511) / 512;
    bn_stats<<<512, 256, 0, stream>>>((const float*)d_out, S1p, S2p, N, rpb);

    bn_apply<<<(N * 16 + 255) / 256, 256, 0, stream>>>(
        (float4*)d_out, S1p, S2p, gamma, betab, N * 16, 1.0f / (float)N);
}

// Round 5
// 285.364 us; speedup vs baseline: 3.3726x; 1.0653x over previous
//
#include <hip/hip_runtime.h>

#define D   64
#define H   8
#define DH  8
#define ED  16
#define QK_SCALE 0.35355339059327373f   // 1/sqrt(8)

__device__ __forceinline__ void fma4(float4& a, float s, const float4& w) {
    a.x += s * w.x; a.y += s * w.y; a.z += s * w.z; a.w += s * w.w;
}

// ---------------------------------------------------------------------------
// K1: node projections q,k,v,x_r ([N,64] each). q pre-scaled by 1/sqrt(8).
// ---------------------------------------------------------------------------
__global__ __launch_bounds__(256) void node_proj(
    const float* __restrict__ x,
    const float* __restrict__ Wq, const float* __restrict__ bq,
    const float* __restrict__ Wk, const float* __restrict__ bk,
    const float* __restrict__ Wv, const float* __restrict__ bv,
    const float* __restrict__ Ws, const float* __restrict__ bs,
    float* __restrict__ q, float* __restrict__ k,
    float* __restrict__ v, float* __restrict__ xr, int N)
{
    __shared__ float sW[4][D * D];          // 64 KB
    {
        const float* wsrc[4] = {Wq, Wk, Wv, Ws};
        for (int m = 0; m < 4; ++m)
            for (int t = threadIdx.x; t < D * D; t += 256)
                sW[m][t] = wsrc[m][t];
    }
    __syncthreads();

    int cg = (threadIdx.x & 15) * 4;
    float4 vbq = *(const float4*)(bq + cg);
    float4 vbk = *(const float4*)(bk + cg);
    float4 vbv = *(const float4*)(bv + cg);
    float4 vbs = *(const float4*)(bs + cg);

    #pragma unroll 1
    for (int it = 0; it < 4; ++it) {
        int node = blockIdx.x * 64 + it * 16 + (threadIdx.x >> 4);
        if (node >= N) return;

        float4 aq = {0,0,0,0}, ak = {0,0,0,0}, av = {0,0,0,0}, as_ = {0,0,0,0};
        const float* xrow = x + (size_t)node * D;

        #pragma unroll
        for (int i = 0; i < D; i += 4) {
            float4 xv = *(const float4*)(xrow + i);
            #pragma unroll
            for (int s = 0; s < 4; ++s) {
                float xs = (&xv.x)[s];
                fma4(aq, xs, *(const float4*)(&sW[0][(i + s) * D + cg]));
                fma4(ak, xs, *(const float4*)(&sW[1][(i + s) * D + cg]));
                fma4(av, xs, *(const float4*)(&sW[2][(i + s) * D + cg]));
                fma4(as_, xs, *(const float4*)(&sW[3][(i + s) * D + cg]));
            }
        }
        aq.x = (aq.x + vbq.x) * QK_SCALE;
        aq.y = (aq.y + vbq.y) * QK_SCALE;
        aq.z = (aq.z + vbq.z) * QK_SCALE;
        aq.w = (aq.w + vbq.w) * QK_SCALE;
        ak.x += vbk.x; ak.y += vbk.y; ak.z += vbk.z; ak.w += vbk.w;
        av.x += vbv.x; av.y += vbv.y; av.z += vbv.z; av.w += vbv.w;
        as_.x += vbs.x; as_.y += vbs.y; as_.z += vbs.z; as_.w += vbs.w;

        size_t o = (size_t)node * D + cg;
        *(float4*)(q  + o) = aq;
        *(float4*)(k  + o) = ak;
        *(float4*)(v  + o) = av;
        *(float4*)(xr + o) = as_;
    }
}

// ---------------------------------------------------------------------------
// K1b: per-node A[n,h,i] = sum_dh q[n,h,dh]*We[i,h*8+dh]  (q already scaled)
//      and qbe[n,h] = sum_dh q[n,h,dh]*be[h*8+dh]. Wave per node.
//      Lane l (h=l>>3,t=l&7) computes A[h,2t], A[h,2t+1].
// ---------------------------------------------------------------------------
__global__ __launch_bounds__(256) void aproj(
    const float* __restrict__ q, const float* __restrict__ We,
    const float* __restrict__ be, float* __restrict__ A,
    float* __restrict__ qbe, int N)
{
    __shared__ float sWe[ED * D];
    __shared__ float sbe[D];
    for (int t = threadIdx.x; t < ED * D; t += 256) sWe[t] = We[t];
    if (threadIdx.x < D) sbe[threadIdx.x] = be[threadIdx.x];
    __syncthreads();

    int lane = threadIdx.x & 63;
    int nid  = blockIdx.x * 4 + (threadIdx.x >> 6);
    if (nid >= N) return;

    int h = lane >> 3, t = lane & 7;
    float qv = q[(size_t)nid * D + lane];
    float a0 = 0.f, a1 = 0.f, qb = 0.f;
    #pragma unroll
    for (int dh = 0; dh < 8; ++dh) {
        float qd = __shfl(qv, (lane & 56) + dh);
        a0 += qd * sWe[(2 * t)     * D + h * 8 + dh];
        a1 += qd * sWe[(2 * t + 1) * D + h * 8 + dh];
        qb += qd * sbe[h * 8 + dh];
    }
    ((float2*)A)[(size_t)nid * 64 + lane] = make_float2(a0, a1);
    if (t == 0) qbe[(size_t)nid * 8 + h] = qb;
}

// ---------------------------------------------------------------------------
// CSR build: histogram -> block scan (3 stages) -> scatter of (src,eid)
// ---------------------------------------------------------------------------
__global__ __launch_bounds__(256) void csr_hist(
    const int* __restrict__ ei, int* __restrict__ cnt, int E)
{
    int gid = blockIdx.x * 256 + threadIdx.x;
    if (gid < E) atomicAdd(&cnt[ei[E + gid]], 1);
}

__global__ __launch_bounds__(256) void scan_a(
    const int* __restrict__ cnt, int* __restrict__ bsum, int N)
{
    __shared__ int red[256];
    int t = threadIdx.x;
    int i = blockIdx.x * 256 + t;
    red[t] = (i < N) ? cnt[i] : 0;
    __syncthreads();
    for (int s = 128; s > 0; s >>= 1) {
        if (t < s) red[t] += red[t + s];
        __syncthreads();
    }
    if (t == 0) bsum[blockIdx.x] = red[0];
}

__global__ __launch_bounds__(256) void scan_b(int* __restrict__ bsum, int nb)
{
    __shared__ int sh[256];
    int t = threadIdx.x;
    int v = (t < nb) ? bsum[t] : 0;
    sh[t] = v;
    __syncthreads();
    for (int s = 1; s < 256; s <<= 1) {
        int a = (t >= s) ? sh[t - s] : 0;
        __syncthreads();
        sh[t] += a;
        __syncthreads();
    }
    if (t < nb) bsum[t] = sh[t] - v;   // exclusive
}

__global__ __launch_bounds__(256) void scan_c(
    const int* __restrict__ cnt, const int* __restrict__ bsum,
    int* __restrict__ row_start, int* __restrict__ cursor, int N, int E)
{
    __shared__ int sh[256];
    int t = threadIdx.x;
    int i = blockIdx.x * 256 + t;
    int v = (i < N) ? cnt[i] : 0;
    sh[t] = v;
    __syncthreads();
    for (int s = 1; s < 256; s <<= 1) {
        int a = (t >= s) ? sh[t - s] : 0;
        __syncthreads();
        sh[t] += a;
        __syncthreads();
    }
    int excl = sh[t] - v + bsum[blockIdx.x];
    if (i < N) { row_start[i] = excl; cursor[i] = excl; }
    if (i == N - 1) row_start[N] = E;
}

__global__ __launch_bounds__(256) void csr_scatter(
    const int* __restrict__ ei, int* __restrict__ cursor,
    int2* __restrict__ csr2, int E)
{
    int gid = blockIdx.x * 256 + threadIdx.x;
    if (gid < E) {
        int d = ei[E + gid];
        int pos = atomicAdd(&cursor[d], 1);
        csr2[pos] = make_int2(ei[gid], gid);
    }
}

// ---------------------------------------------------------------------------
// K2: pull gather. wave = dst node (grid-stride), lane = column.
//     logit = q.k + ea.A[dst] + qbe[dst]  (3 FMA + 3 shfl per edge)
//     V e-side via s[h,i] accumulators, recombined once per node.
//     Fused: alpha-norm, beta gate, out write, block BN partial sums.
// ---------------------------------------------------------------------------
__global__ __launch_bounds__(256) void node_gather(
    const float* __restrict__ ea,
    const int*   __restrict__ row_start, // [N+1]
    const int2*  __restrict__ csr2,      // [E] (src, eid)
    const float* __restrict__ We, const float* __restrict__ be,
    const float* __restrict__ q, const float* __restrict__ k,
    const float* __restrict__ v, const float* __restrict__ xr,
    const float* __restrict__ A, const float* __restrict__ qbe,
    const float* __restrict__ Wbeta,
    float* __restrict__ out, float* __restrict__ S1p, float* __restrict__ S2p,
    int N)
{
    __shared__ float l1[4][D];
    __shared__ float l2[4][D];
    int lane = threadIdx.x & 63;
    int w    = threadIdx.x >> 6;
    int t    = lane & 7;

    float rWe[ED];
    #pragma unroll
    for (int i = 0; i < ED; ++i) rWe[i] = We[i * D + lane];
    float bev = be[lane];
    float wb0 = Wbeta[lane], wb1 = Wbeta[D + lane], wb2 = Wbeta[2 * D + lane];

    float s1bn = 0.f, s2bn = 0.f;
    int stride = gridDim.x * 4;

    for (int nid = blockIdx.x * 4 + w; nid < N; nid += stride) {
        int rs  = row_start[nid];
        int deg = row_start[nid + 1] - rs;

        float  qv   = q[(size_t)nid * D + lane];
        float2 a01  = ((const float2*)A)[(size_t)nid * 64 + lane];
        float  qbeh = qbe[(size_t)nid * 8 + (lane >> 3)];

        float acc = 0.f, den = 0.f, s0 = 0.f, s1 = 0.f;

        int2 se = make_int2(0, 0);
        if (lane < deg) se = csr2[rs + lane];

        int nb = (deg < 64) ? deg : 64;
        for (int j0 = 0; j0 < nb; j0 += 4) {
            int m = nb - j0; if (m > 4) m = 4;
            float kvv[4], vvv[4]; float2 ea2[4];
            #pragma unroll
            for (int j = 0; j < 4; ++j) {
                int jj  = (j < m) ? (j0 + j) : j0;
                int s   = __builtin_amdgcn_readlane(se.x, jj);
                int eid = __builtin_amdgcn_readlane(se.y, jj);
                kvv[j] = k[(size_t)s * D + lane];
                vvv[j] = v[(size_t)s * D + lane];
                ea2[j] = *(const float2*)(ea + (size_t)eid * ED + 2 * t);
            }
            #pragma unroll
            for (int j = 0; j < 4; ++j) {
                if (j < m) {
                    float c = qv * kvv[j] + ea2[j].x * a01.x + ea2[j].y * a01.y;
                    c += __shfl_xor(c, 1);
                    c += __shfl_xor(c, 2);
                    c += __shfl_xor(c, 4);
                    float p = __expf(c + qbeh);
                    acc += p * vvv[j];
                    den += p;
                    s0  += p * ea2[j].x;
                    s1  += p * ea2[j].y;
                }
            }
        }
        // rare fallback: degree > 64
        for (int j = 64; j < deg; ++j) {
            int2 se2 = csr2[rs + j];
            float kvv = k[(size_t)se2.x * D + lane];
            float vvv = v[(size_t)se2.x * D + lane];
            float2 e2 = *(const float2*)(ea + (size_t)se2.y * ED + 2 * t);
            float c = qv * kvv + e2.x * a01.x + e2.y * a01.y;
            c += __shfl_xor(c, 1);
            c += __shfl_xor(c, 2);
            c += __shfl_xor(c, 4);
            float p = __expf(c + qbeh);
            acc += p * vvv; den += p;
            s0 += p * e2.x; s1 += p * e2.y;
        }

        // recombine e-side V: esum_l = sum_i We[i,l]*s[h,i]
        float esum = 0.f;
        #pragma unroll
        for (int i = 0; i < ED; ++i) {
            int srcl = (lane & 56) + (i >> 1);
            float sv = (i & 1) ? __shfl(s1, srcl) : __shfl(s0, srcl);
            esum += sv * rWe[i];
        }

        float o   = (acc + esum + bev * den) / (den + 1e-16f);
        float xrv = xr[(size_t)nid * D + lane];
        float tb  = o * wb0 + xrv * wb1 + (o - xrv) * wb2;
        #pragma unroll
        for (int s = 1; s < 64; s <<= 1) tb += __shfl_xor(tb, s);
        float g  = 1.f / (1.f + __expf(-tb));
        float o2 = g * xrv + (1.f - g) * o;
        out[(size_t)nid * D + lane] = o2;
        s1bn += o2; s2bn += o2 * o2;
    }

    l1[w][lane] = s1bn; l2[w][lane] = s2bn;
    __syncthreads();
    if (threadIdx.x < D) {
        float a = l1[0][threadIdx.x] + l1[1][threadIdx.x]
                + l1[2][threadIdx.x] + l1[3][threadIdx.x];
        float b = l2[0][threadIdx.x] + l2[1][threadIdx.x]
                + l2[2][threadIdx.x] + l2[3][threadIdx.x];
        unsafeAtomicAdd(&S1p[threadIdx.x * 64], a);
        unsafeAtomicAdd(&S2p[threadIdx.x * 64], b);
    }
}

// ---------------------------------------------------------------------------
// K4: batchnorm finalize + apply + LeakyReLU, float4 in place on d_out.
// ---------------------------------------------------------------------------
__global__ __launch_bounds__(256) void bn_apply(
    float4* __restrict__ out, const float* __restrict__ S1p,
    const float* __restrict__ S2p, const float* __restrict__ gamma,
    const float* __restrict__ beta, int total4, float invN)
{
    int gid = blockIdx.x * 256 + threadIdx.x;
    if (gid >= total4) return;
    int col = (gid & 15) * 4;
    float4 g4 = *(const float4*)(gamma + col);
    float4 b4 = *(const float4*)(beta + col);
    float4 y  = out[gid];
    #pragma unroll
    for (int j = 0; j < 4; ++j) {
        float mean = S1p[(col + j) * 64] * invN;
        float var  = S2p[(col + j) * 64] * invN - mean * mean;
        float sc   = (&g4.x)[j] * rsqrtf(var + 1e-5f);
        float sh   = (&b4.x)[j] - mean * sc;
        float tv   = (&y.x)[j] * sc + sh;
        (&y.x)[j]  = (tv >= 0.f) ? tv : 0.01f * tv;
    }
    out[gid] = y;
}

// ---------------------------------------------------------------------------
extern "C" void kernel_launch(void* const* d_in, const int* in_sizes, int n_in,
                              void* d_out, int out_size, void* d_ws, size_t ws_size,
                              hipStream_t stream)
{
    const float* x     = (const float*)d_in[0];
    const int*   ei    = (const int*)  d_in[1];
    const float* ea    = (const float*)d_in[2];
    const float* Wq    = (const float*)d_in[3];
    const float* bq    = (const float*)d_in[4];
    const float* Wk    = (const float*)d_in[5];
    const float* bk    = (const float*)d_in[6];
    const float* Wv    = (const float*)d_in[7];
    const float* bv    = (const float*)d_in[8];
    const float* We    = (const float*)d_in[9];
    const float* be    = (const float*)d_in[10];
    const float* Wskip = (const float*)d_in[11];
    const float* bskip = (const float*)d_in[12];
    const float* Wbeta = (const float*)d_in[13];
    const float* gamma = (const float*)d_in[14];
    const float* betab = (const float*)d_in[15];

    int N = in_sizes[0] / D;   // 50000
    int E = in_sizes[1] / 2;   // 800000

    // ws layout (int units)
    int*   ws        = (int*)d_ws;
    int*   cnt       = ws;                         // 50000 (also scatter cursor)
    float* S1p       = (float*)(ws + 50000);       // 4096 padded col sums
    float* S2p       = (float*)(ws + 54096);       // 4096
    int*   row_start = ws + 58192;                 // 50004
    int*   bsum      = ws + 108196;                // 50000 (scan block sums)
    int2*  csr2      = (int2*)(ws + 158200);       // 2*800000 ints, 8B aligned
    float* q         = (float*)(ws + 1758208);     // 3.2M, 16B aligned
    float* k         = q + 3200000;
    float* v         = k + 3200000;
    float* xr        = v + 3200000;
    float* A         = xr + 3200000;               // 6.4M
    float* qbe       = A + 6400000;                // 400000

    // zero cnt + S1p + S2p (contiguous)
    hipMemsetAsync(d_ws, 0, (size_t)58192 * sizeof(int), stream);

    node_proj<<<(N + 63) / 64, 256, 0, stream>>>(
        x, Wq, bq, Wk, bk, Wv, bv, Wskip, bskip, q, k, v, xr, N);

    aproj<<<(N + 3) / 4, 256, 0, stream>>>(q, We, be, A, qbe, N);

    int nb = (N + 255) / 256;   // 196
    csr_hist<<<(E + 255) / 256, 256, 0, stream>>>(ei, cnt, E);
    scan_a<<<nb, 256, 0, stream>>>(cnt, bsum, N);
    scan_b<<<1, 256, 0, stream>>>(bsum, nb);
    scan_c<<<nb, 256, 0, stream>>>(cnt, bsum, row_start, cnt, N, E);
    csr_scatter<<<(E + 255) / 256, 256, 0, stream>>>(ei, cnt, csr2, E);

    node_gather<<<1024, 256, 0, stream>>>(
        ea, row_start, csr2, We, be, q, k, v, xr, A, qbe, Wbeta,
        (float*)d_out, S1p, S2p, N);

    bn_apply<<<(N * 16 + 255) / 256, 256, 0, stream>>>(
        (float4*)d_out, S1p, S2p, gamma, betab, N * 16, 1.0f / (float)N);
}